// Round 11
// baseline (213.346 us; speedup 1.0000x reference)
//
#include <hip/hip_runtime.h>

#define NN 100000
#define NE 1200000
#define NG 2048
#define NBK 391           // cdiv(NN,256) buckets of 256 nodes
#define CAPQ 4096         // raw records capacity per bucket (mean 3070, >18 sigma)
#define CAPE 5120         // padded CSR capacity per bucket

static inline int cdiv(long long a, int b) { return (int)((a + b - 1) / b); }

// ---------------- bf16 helpers (RNE pack, shift unpack) ----------------
__device__ __forceinline__ unsigned short f2bf(float f) {
    unsigned int u = __float_as_uint(f);
    u += 0x7fffu + ((u >> 16) & 1u);
    return (unsigned short)(u >> 16);
}
__device__ __forceinline__ unsigned int pack2(float a, float b) {
    return (unsigned int)f2bf(a) | ((unsigned int)f2bf(b) << 16);
}
__device__ __forceinline__ float lo2f(unsigned int w) { return __uint_as_float(w << 16); }
__device__ __forceinline__ float hi2f(unsigned int w) { return __uint_as_float(w & 0xffff0000u); }

// ---------------- init: bucket cursors + sentinel rows ----------------
__global__ void k_init(int* __restrict__ gcur, uint4* __restrict__ A16,
                       uint4* __restrict__ B16, uint4* __restrict__ h1p16,
                       uint4* __restrict__ g1p16, float* __restrict__ dinv) {
    int g = blockIdx.x * blockDim.x + threadIdx.x;
    if (g < NBK) gcur[g] = g * CAPQ;
    if (g == NBK) dinv[NN] = 0.f;
    uint4 z = make_uint4(0u, 0u, 0u, 0u);
    int s = g - 512;
    if (s >= 0 && s < 6) {
        A16[(size_t)NN * 6 + s] = z;
        B16[(size_t)NN * 6 + s] = z;
    } else if (s >= 6 && s < 8) {
        h1p16[(size_t)NN * 2 + (s - 6)] = z;
        g1p16[(size_t)NN * 2 + (s - 6)] = z;
    }
}

// ---------------- phase 1: partition edges bucket-major into pairs (int4, 512 blocks) ----------------
__global__ __launch_bounds__(256) void k_part(const int4* __restrict__ row4,
                                              const int4* __restrict__ col4,
                                              int* __restrict__ gcur,
                                              int* __restrict__ pairs, int E4) {
    __shared__ int hcnt[NBK];
    __shared__ int hbase[NBK];
    int chunk = (E4 + gridDim.x - 1) / gridDim.x;
    int beg = blockIdx.x * chunk;
    int end = min(E4, beg + chunk);
    for (int j = threadIdx.x; j < NBK; j += 256) hcnt[j] = 0;
    __syncthreads();
    for (int g = beg + threadIdx.x; g < end; g += 256) {
        int4 c = col4[g];
        atomicAdd(&hcnt[c.x >> 8], 1);
        atomicAdd(&hcnt[c.y >> 8], 1);
        atomicAdd(&hcnt[c.z >> 8], 1);
        atomicAdd(&hcnt[c.w >> 8], 1);
    }
    __syncthreads();
    for (int j = threadIdx.x; j < NBK; j += 256) {
        int c = hcnt[j];
        hbase[j] = c > 0 ? atomicAdd(&gcur[j], c) : 0;
        hcnt[j] = 0;
    }
    __syncthreads();
    for (int g = beg + threadIdx.x; g < end; g += 256) {
        int4 c = col4[g];
        int4 r = row4[g];
        int b0 = c.x >> 8, b1 = c.y >> 8, b2 = c.z >> 8, b3 = c.w >> 8;
        int p0 = hbase[b0] + atomicAdd(&hcnt[b0], 1);
        if (p0 < (b0 + 1) * CAPQ) pairs[p0] = ((c.x & 255) << 17) | r.x;
        int p1 = hbase[b1] + atomicAdd(&hcnt[b1], 1);
        if (p1 < (b1 + 1) * CAPQ) pairs[p1] = ((c.y & 255) << 17) | r.y;
        int p2 = hbase[b2] + atomicAdd(&hcnt[b2], 1);
        if (p2 < (b2 + 1) * CAPQ) pairs[p2] = ((c.z & 255) << 17) | r.z;
        int p3 = hbase[b3] + atomicAdd(&hcnt[b3], 1);
        if (p3 < (b3 + 1) * CAPQ) pairs[p3] = ((c.w & 255) << 17) | r.w;
    }
}

// ---------------- phase 2: per-bucket count/scan/dinv/rowptr + staged scatter (int4) ----------------
// packed rowptr: bits[0:20) = beg>>2, bits[20:31) = paddedCount>>2
__global__ __launch_bounds__(256) void k_bucket(const int* __restrict__ pairs,
                                                const int* __restrict__ gcur,
                                                int* __restrict__ esrc,
                                                int* __restrict__ rowptrp,
                                                float* __restrict__ dinv, int N) {
    __shared__ int stage[CAPE];
    __shared__ int lcnt[256];
    __shared__ int s[256];
    __shared__ int tot;
    int b = blockIdx.x;
    int base = b << 8;
    int nn = min(256, N - base);
    int qb = b * CAPQ;
    int qe = min(gcur[b], qb + CAPQ);
    int cnt = qe - qb;
    int n4 = cnt >> 2, tail = cnt & 3;
    const int4* pairs4 = (const int4*)(pairs + qb);
    int tid = threadIdx.x;
    lcnt[tid] = 0;
    __syncthreads();
    for (int g = tid; g < n4; g += 256) {
        int4 v = pairs4[g];
        atomicAdd(&lcnt[v.x >> 17], 1);
        atomicAdd(&lcnt[v.y >> 17], 1);
        atomicAdd(&lcnt[v.z >> 17], 1);
        atomicAdd(&lcnt[v.w >> 17], 1);
    }
    if (tid < tail) atomicAdd(&lcnt[pairs[qb + n4 * 4 + tid] >> 17], 1);
    __syncthreads();
    int c = lcnt[tid];
    int pc = (c + 3) & ~3;
    s[tid] = pc;
    __syncthreads();
    for (int off = 1; off < 256; off <<= 1) {
        int t = (tid >= off) ? s[tid - off] : 0;
        __syncthreads();
        s[tid] += t;
        __syncthreads();
    }
    int myofs = s[tid] - pc;
    if (tid == 255) tot = s[255];
    __syncthreads();
    int padded = tot;
    if (tid < nn) {
        dinv[base + tid] = c > 0 ? rsqrtf((float)c) : 0.f;
        rowptrp[base + tid] = ((b * CAPE + myofs) >> 2) | ((pc >> 2) << 20);
    }
    int4* stage4 = (int4*)stage;
    int pad4 = padded >> 2;
    int4 sent = make_int4(N, N, N, N);
    for (int i = tid; i < pad4; i += 256) stage4[i] = sent;
    lcnt[tid] = myofs;
    __syncthreads();
    for (int g = tid; g < n4; g += 256) {
        int4 v = pairs4[g];
        int pos;
        pos = atomicAdd(&lcnt[v.x >> 17], 1); stage[pos] = v.x & 0x1FFFF;
        pos = atomicAdd(&lcnt[v.y >> 17], 1); stage[pos] = v.y & 0x1FFFF;
        pos = atomicAdd(&lcnt[v.z >> 17], 1); stage[pos] = v.z & 0x1FFFF;
        pos = atomicAdd(&lcnt[v.w >> 17], 1); stage[pos] = v.w & 0x1FFFF;
    }
    if (tid < tail) {
        int v = pairs[qb + n4 * 4 + tid];
        int pos = atomicAdd(&lcnt[v >> 17], 1);
        stage[pos] = v & 0x1FFFF;
    }
    __syncthreads();
    int4* esrc4 = (int4*)(esrc + b * CAPE);
    for (int i = tid; i < pad4; i += 256) esrc4[i] = stage4[i];
}

// ---------------- fused layer-1 transforms: A16=(x@w1i)*dinv (bf16), R=x@w1r+b (fp32) ----------------
__global__ void k_mmAR(const float* __restrict__ x,
                       const float* __restrict__ w1i, const float* __restrict__ w1r,
                       const float* __restrict__ b1, const float* __restrict__ dinv,
                       ushort4* __restrict__ A16s, float4* __restrict__ R4, int N) {
    __shared__ float4 Wi[900];   // [3][75][4] float4
    __shared__ float4 Wr[900];
    __shared__ float4 Bs[12];
    const float4* wi4 = (const float4*)w1i;
    const float4* wr4 = (const float4*)w1r;
    for (int i = threadIdx.x; i < 900; i += blockDim.x) { Wi[i] = wi4[i]; Wr[i] = wr4[i]; }
    if (threadIdx.x < 12) Bs[threadIdx.x] = ((const float4*)b1)[threadIdx.x];
    __syncthreads();
    const int total = N * 12;
    const int stride = gridDim.x * blockDim.x;
    for (int idx = blockIdx.x * blockDim.x + threadIdx.x; idx < total; idx += stride) {
        int n = idx / 12;
        int q = idx - n * 12;
        int k = q >> 2, o4 = q & 3;
        const float* xp = x + (size_t)n * 75;
        const float4* wpi = Wi + (k * 75) * 4 + o4;
        const float4* wpr = Wr + (k * 75) * 4 + o4;
        float aix = 0.f, aiy = 0.f, aiz = 0.f, aiw = 0.f;
        float4 br = Bs[q];
        float arx = br.x, ary = br.y, arz = br.z, arw = br.w;
#pragma unroll
        for (int f = 0; f < 75; ++f) {
            float xv = xp[f];
            float4 wi = wpi[f * 4];
            float4 wr = wpr[f * 4];
            aix = fmaf(xv, wi.x, aix);
            aiy = fmaf(xv, wi.y, aiy);
            aiz = fmaf(xv, wi.z, aiz);
            aiw = fmaf(xv, wi.w, aiw);
            arx = fmaf(xv, wr.x, arx);
            ary = fmaf(xv, wr.y, ary);
            arz = fmaf(xv, wr.z, arz);
            arw = fmaf(xv, wr.w, arw);
        }
        float dn = dinv[n];
        ushort4 sa;
        sa.x = f2bf(aix * dn); sa.y = f2bf(aiy * dn);
        sa.z = f2bf(aiz * dn); sa.w = f2bf(aiw * dn);
        A16s[(size_t)n * 12 + q] = sa;
        R4[idx] = make_float4(arx, ary, arz, arw);
    }
}

// ---------------- 48-wide CSR prop over bf16 rows (6 threads/node, 2x edge unroll) ----------------
#define ACC8(W)                                                     \
    a0 += lo2f(W.x); a1 += hi2f(W.x); a2 += lo2f(W.y); a3 += hi2f(W.y); \
    a4 += lo2f(W.z); a5 += hi2f(W.z); a6 += lo2f(W.w); a7 += hi2f(W.w);

template <int HAS_R, int COMPUTE_S, int SCALE_OUT>
__global__ void k_prop48(const uint4* __restrict__ src, const float4* __restrict__ R4,
                         const int* __restrict__ rowptrp, const int* __restrict__ esrc,
                         const float* __restrict__ dinv, float* __restrict__ sv,
                         uint4* __restrict__ dst, int N) {
    const int total = N * 6;
    const int stride = gridDim.x * blockDim.x;
    for (int idx = blockIdx.x * blockDim.x + threadIdx.x; idx < total; idx += stride) {
        int n = idx / 6;
        int q = idx - n * 6;
        int rp = rowptrp[n];
        int beg = (rp & 0xFFFFF) << 2;
        int end = beg + ((rp >> 20) << 2);
        float a0 = 0.f, a1 = 0.f, a2 = 0.f, a3 = 0.f, a4 = 0.f, a5 = 0.f, a6 = 0.f, a7 = 0.f;
        float sd = 0.f;
        int p = beg;
        for (; p + 8 <= end; p += 8) {
            int4 e0 = *(const int4*)(esrc + p);
            int4 e1 = *(const int4*)(esrc + p + 4);
            uint4 w0 = src[(size_t)e0.x * 6 + q];
            uint4 w1 = src[(size_t)e0.y * 6 + q];
            uint4 w2 = src[(size_t)e0.z * 6 + q];
            uint4 w3 = src[(size_t)e0.w * 6 + q];
            uint4 w4 = src[(size_t)e1.x * 6 + q];
            uint4 w5 = src[(size_t)e1.y * 6 + q];
            uint4 w6 = src[(size_t)e1.z * 6 + q];
            uint4 w7 = src[(size_t)e1.w * 6 + q];
            ACC8(w0); ACC8(w1); ACC8(w2); ACC8(w3);
            ACC8(w4); ACC8(w5); ACC8(w6); ACC8(w7);
            if (COMPUTE_S) {
                if (q == 0)
                    sd += ((dinv[e0.x] + dinv[e0.y]) + (dinv[e0.z] + dinv[e0.w]))
                        + ((dinv[e1.x] + dinv[e1.y]) + (dinv[e1.z] + dinv[e1.w]));
            }
        }
        if (p < end) {
            int4 e = *(const int4*)(esrc + p);
            uint4 w0 = src[(size_t)e.x * 6 + q];
            uint4 w1 = src[(size_t)e.y * 6 + q];
            uint4 w2 = src[(size_t)e.z * 6 + q];
            uint4 w3 = src[(size_t)e.w * 6 + q];
            ACC8(w0); ACC8(w1); ACC8(w2); ACC8(w3);
            if (COMPUTE_S) {
                if (q == 0)
                    sd += (dinv[e.x] + dinv[e.y]) + (dinv[e.z] + dinv[e.w]);
            }
        }
        float dn = dinv[n];
        float v0 = a0 * dn, v1 = a1 * dn, v2 = a2 * dn, v3 = a3 * dn;
        float v4 = a4 * dn, v5 = a5 * dn, v6 = a6 * dn, v7 = a7 * dn;
        if (HAS_R) {
            float4 r0 = R4[(size_t)n * 12 + q * 2];
            float4 r1 = R4[(size_t)n * 12 + q * 2 + 1];
            v0 = fmaxf(v0 + r0.x, 0.f); v1 = fmaxf(v1 + r0.y, 0.f);
            v2 = fmaxf(v2 + r0.z, 0.f); v3 = fmaxf(v3 + r0.w, 0.f);
            v4 = fmaxf(v4 + r1.x, 0.f); v5 = fmaxf(v5 + r1.y, 0.f);
            v6 = fmaxf(v6 + r1.z, 0.f); v7 = fmaxf(v7 + r1.w, 0.f);
        }
        if (SCALE_OUT) {
            v0 *= dn; v1 *= dn; v2 *= dn; v3 *= dn;
            v4 *= dn; v5 *= dn; v6 *= dn; v7 *= dn;
        }
        uint4 o;
        o.x = pack2(v0, v1); o.y = pack2(v2, v3);
        o.z = pack2(v4, v5); o.w = pack2(v6, v7);
        dst[(size_t)n * 6 + q] = o;
        if (COMPUTE_S) {
            if (q == 0) sv[n] = sd * dn;
        }
    }
}

// ---------------- layer-1 t=1 epilogue: h1p16 = dinv*mean_k relu(A@w1w+R); z0 = h1.u0 ----------------
__global__ void k_post1(const uint4* __restrict__ A16, const float4* __restrict__ R4,
                        const float* __restrict__ w1w, const float* __restrict__ dinv,
                        const float* __restrict__ u,
                        ushort4* __restrict__ h1p16s, float* __restrict__ z0, int N) {
    __shared__ float4 Ws[192];  // [3][16][4] float4 of w1w[k][i][o]
    const float4* w4 = (const float4*)w1w;
    for (int i = threadIdx.x; i < 192; i += blockDim.x) Ws[i] = w4[i];
    __syncthreads();
    const int total = N * 4;
    const int stride = gridDim.x * blockDim.x;
    for (int idx = blockIdx.x * blockDim.x + threadIdx.x; idx < total; idx += stride) {
        int n = idx >> 2;
        int o4 = idx & 3;
        const uint4* ap = A16 + (size_t)n * 6;
        float av[48];
#pragma unroll
        for (int c6 = 0; c6 < 6; ++c6) {
            uint4 w = ap[c6];
            av[c6 * 8 + 0] = lo2f(w.x); av[c6 * 8 + 1] = hi2f(w.x);
            av[c6 * 8 + 2] = lo2f(w.y); av[c6 * 8 + 3] = hi2f(w.y);
            av[c6 * 8 + 4] = lo2f(w.z); av[c6 * 8 + 5] = hi2f(w.z);
            av[c6 * 8 + 6] = lo2f(w.w); av[c6 * 8 + 7] = hi2f(w.w);
        }
        float4 sum = make_float4(0.f, 0.f, 0.f, 0.f);
#pragma unroll
        for (int k = 0; k < 3; ++k) {
            float4 d = R4[(size_t)n * 12 + k * 4 + o4];
#pragma unroll
            for (int i = 0; i < 16; ++i) {
                float a = av[k * 16 + i];
                float4 w = Ws[(k * 16 + i) * 4 + o4];
                d.x = fmaf(a, w.x, d.x);
                d.y = fmaf(a, w.y, d.y);
                d.z = fmaf(a, w.z, d.z);
                d.w = fmaf(a, w.w, d.w);
            }
            d.x = fmaxf(d.x, 0.f); d.y = fmaxf(d.y, 0.f);
            d.z = fmaxf(d.z, 0.f); d.w = fmaxf(d.w, 0.f);
            sum.x += d.x; sum.y += d.y; sum.z += d.z; sum.w += d.w;
        }
        const float third = 1.0f / 3.0f;
        sum.x *= third; sum.y *= third; sum.z *= third; sum.w *= third;
        float dn = dinv[n];
        ushort4 sp;
        sp.x = f2bf(sum.x * dn); sp.y = f2bf(sum.y * dn);
        sp.z = f2bf(sum.z * dn); sp.w = f2bf(sum.w * dn);
        h1p16s[(size_t)n * 4 + o4] = sp;
        float4 u0q = ((const float4*)u)[o4];
        float part = sum.x * u0q.x + sum.y * u0q.y + sum.z * u0q.z + sum.w * u0q.w;
        part += __shfl_down(part, 2, 4);
        part += __shfl_down(part, 1, 4);
        if (o4 == 0) z0[n] = part;
    }
}

// combine 8 accumulators across the 4 edge-slice lanes (stride 2 in an 8-lane group)
#define COMB8()                                                        \
    a0 += __shfl_down(a0, 4, 8); a1 += __shfl_down(a1, 4, 8);          \
    a2 += __shfl_down(a2, 4, 8); a3 += __shfl_down(a3, 4, 8);          \
    a4 += __shfl_down(a4, 4, 8); a5 += __shfl_down(a5, 4, 8);          \
    a6 += __shfl_down(a6, 4, 8); a7 += __shfl_down(a7, 4, 8);          \
    a0 += __shfl_down(a0, 2, 8); a1 += __shfl_down(a1, 2, 8);          \
    a2 += __shfl_down(a2, 2, 8); a3 += __shfl_down(a3, 2, 8);          \
    a4 += __shfl_down(a4, 2, 8); a5 += __shfl_down(a5, 2, 8);          \
    a6 += __shfl_down(a6, 2, 8); a7 += __shfl_down(a7, 2, 8);

// ---------------- prop16 #1: g1 = A_n h1; 8 threads/node (4 edge-slices x 2 halves) ----------------
__global__ void k_prop16z(const uint4* __restrict__ h1p16,
                          const int* __restrict__ rowptrp, const int* __restrict__ esrc,
                          const float* __restrict__ dinv, const float* __restrict__ u,
                          uint4* __restrict__ g1p16, float* __restrict__ z1, int N) {
    const int total = N * 8;
    const int stride = gridDim.x * blockDim.x;
    for (int idx = blockIdx.x * blockDim.x + threadIdx.x; idx < total; idx += stride) {
        int n = idx >> 3;
        int r = idx & 7;
        int q = r & 1;
        int es = r >> 1;
        int rp = rowptrp[n];
        int beg = ((rp & 0xFFFFF) << 2) + es * 4;
        int end = ((rp & 0xFFFFF) << 2) + ((rp >> 20) << 2);
        float a0 = 0.f, a1 = 0.f, a2 = 0.f, a3 = 0.f, a4 = 0.f, a5 = 0.f, a6 = 0.f, a7 = 0.f;
        for (int p = beg; p < end; p += 16) {
            int4 e = *(const int4*)(esrc + p);
            uint4 w0 = h1p16[(size_t)e.x * 2 + q];
            uint4 w1 = h1p16[(size_t)e.y * 2 + q];
            uint4 w2 = h1p16[(size_t)e.z * 2 + q];
            uint4 w3 = h1p16[(size_t)e.w * 2 + q];
            ACC8(w0); ACC8(w1); ACC8(w2); ACC8(w3);
        }
        COMB8();
        // lanes r<2 (es==0) hold full sums for their feature half q
        float dn = dinv[n];
        float v0 = a0 * dn, v1 = a1 * dn, v2 = a2 * dn, v3 = a3 * dn;
        float v4 = a4 * dn, v5 = a5 * dn, v6 = a6 * dn, v7 = a7 * dn;
        const float4* u4 = (const float4*)(u + 16);
        float4 ua = u4[q * 2], ub = u4[q * 2 + 1];
        float part = v0 * ua.x + v1 * ua.y + v2 * ua.z + v3 * ua.w
                   + v4 * ub.x + v5 * ub.y + v6 * ub.z + v7 * ub.w;
        part += __shfl_down(part, 1, 8);
        if (r == 0) z1[n] = part;
        if (r < 2) {
            uint4 o;
            o.x = pack2(v0 * dn, v1 * dn); o.y = pack2(v2 * dn, v3 * dn);
            o.z = pack2(v4 * dn, v5 * dn); o.w = pack2(v6 * dn, v7 * dn);
            g1p16[(size_t)n * 2 + q] = o;
        }
    }
}

// ---------------- prop16 #2 fused with score/pool; 8 threads/node ----------------
__global__ void k_score(const uint4* __restrict__ g1p16,
                        const int* __restrict__ rowptrp, const int* __restrict__ esrc,
                        const float* __restrict__ dinv, const float* __restrict__ u,
                        const float* __restrict__ z0, const float* __restrict__ z1,
                        const float* __restrict__ sv, const int* __restrict__ batch,
                        float* __restrict__ out, int N) {
    const int total = N * 8;
    const int stride = gridDim.x * blockDim.x;
    for (int idx = blockIdx.x * blockDim.x + threadIdx.x; idx < total; idx += stride) {
        int n = idx >> 3;
        int r = idx & 7;
        int q = r & 1;
        int es = r >> 1;
        int rp = rowptrp[n];
        int beg = ((rp & 0xFFFFF) << 2) + es * 4;
        int end = ((rp & 0xFFFFF) << 2) + ((rp >> 20) << 2);
        float a0 = 0.f, a1 = 0.f, a2 = 0.f, a3 = 0.f, a4 = 0.f, a5 = 0.f, a6 = 0.f, a7 = 0.f;
        for (int p = beg; p < end; p += 16) {
            int4 e = *(const int4*)(esrc + p);
            uint4 w0 = g1p16[(size_t)e.x * 2 + q];
            uint4 w1 = g1p16[(size_t)e.y * 2 + q];
            uint4 w2 = g1p16[(size_t)e.z * 2 + q];
            uint4 w3 = g1p16[(size_t)e.w * 2 + q];
            ACC8(w0); ACC8(w1); ACC8(w2); ACC8(w3);
        }
        COMB8();
        float dn = dinv[n];
        const float4* u4 = (const float4*)(u + 32);
        float4 ua = u4[q * 2], ub = u4[q * 2 + 1];
        float part = (a0 * dn) * ua.x + (a1 * dn) * ua.y + (a2 * dn) * ua.z + (a3 * dn) * ua.w
                   + (a4 * dn) * ub.x + (a5 * dn) * ub.y + (a6 * dn) * ub.z + (a7 * dn) * ub.w;
        part += __shfl_down(part, 1, 8);
        if (r == 0) {
            float v = part + z0[n] + z1[n] + sv[n] * u[48] + u[49];
            atomicAdd(&out[batch[n]], v);
        }
    }
}

// ---------------- precombine layer-2+head weights; blocks 1..8 init out ----------------
__global__ void k_comb(const float* __restrict__ w2i, const float* __restrict__ w2w,
                       const float* __restrict__ w2r, const float* __restrict__ b2,
                       const float* __restrict__ wg, const float* __restrict__ bg,
                       float* __restrict__ u, float* __restrict__ out) {
    if (blockIdx.x > 0) {
        int g = (blockIdx.x - 1) * 256 + threadIdx.x;
        if (g < NG) out[g] = bg[0];
        return;
    }
    __shared__ float t[3][64];
    int tid = threadIdx.x;
    if (tid < 64) {
#pragma unroll
        for (int k = 0; k < 3; ++k) {
            float a = 0.f;
            for (int j = 0; j < 64; ++j) a = fmaf(w2w[k * 4096 + tid * 64 + j], wg[j], a);
            t[k][tid] = a;
        }
    }
    __syncthreads();
    if (tid < 64) {
        float wgv = wg[tid];
        float tk0 = t[0][tid], tk1 = t[1][tid], tk2 = t[2][tid];
        const float third = 1.0f / 3.0f;
        for (int j = 0; j < 16; ++j) {
            float wi0 = w2i[j * 64 + tid], wi1 = w2i[1024 + j * 64 + tid], wi2 = w2i[2048 + j * 64 + tid];
            float wr0 = w2r[j * 64 + tid], wr1 = w2r[1024 + j * 64 + tid], wr2 = w2r[2048 + j * 64 + tid];
            float a2 = wi0 * tk0 + wi1 * tk1 + wi2 * tk2;
            float a1 = wr0 * tk0 + wr1 * tk1 + wr2 * tk2;
            float a0 = (wr0 + wr1 + wr2) * wgv;
#pragma unroll
            for (int off = 32; off > 0; off >>= 1) {
                a2 += __shfl_down(a2, off, 64);
                a1 += __shfl_down(a1, off, 64);
                a0 += __shfl_down(a0, off, 64);
            }
            if (tid == 0) {
                u[j] = a0 * third;
                u[16 + j] = a1 * third;
                u[32 + j] = a2 * third;
            }
        }
        float b0 = b2[tid], b1v = b2[64 + tid], b2v = b2[128 + tid];
        float c0 = b0 * tk0 + b1v * tk1 + b2v * tk2;
        float c1 = (b0 + b1v + b2v) * wgv;
#pragma unroll
        for (int off = 32; off > 0; off >>= 1) {
            c0 += __shfl_down(c0, off, 64);
            c1 += __shfl_down(c1, off, 64);
        }
        if (tid == 0) {
            u[48] = c0 * third;
            u[49] = c1 * third;
        }
    }
}

extern "C" void kernel_launch(void* const* d_in, const int* in_sizes, int n_in,
                              void* d_out, int out_size, void* d_ws, size_t ws_size,
                              hipStream_t stream) {
    const float* x   = (const float*)d_in[0];
    const int*   ei  = (const int*)d_in[1];
    const int*   batch = (const int*)d_in[2];
    const float* w1i = (const float*)d_in[3];
    const float* w1w = (const float*)d_in[4];
    const float* w1r = (const float*)d_in[5];
    const float* w1b = (const float*)d_in[6];
    const float* w2i = (const float*)d_in[7];
    const float* w2w = (const float*)d_in[8];
    const float* w2r = (const float*)d_in[9];
    const float* w2b = (const float*)d_in[10];
    const float* wg  = (const float*)d_in[11];
    const float* bg  = (const float*)d_in[12];
    float* out = (float*)d_out;

    // workspace layout (all 16B-aligned)
    uint4* A16   = (uint4*)d_ws;                          // [(N+1)*6] uint4 = bf16[N+1][48]
    uint4* B16   = A16 + (size_t)(NN + 1) * 6;            // same
    float* R     = (float*)(B16 + (size_t)(NN + 1) * 6);  // fp32 [N][48]
    uint4* h1p16 = (uint4*)(R + (size_t)NN * 48);         // [(N+1)*2] uint4 = bf16[N+1][16]
    uint4* g1p16 = h1p16 + (size_t)(NN + 1) * 2;          // same
    float* dinv  = (float*)(g1p16 + (size_t)(NN + 1) * 2);// [N+1] pad to 100004
    float* sv    = dinv + 100004;                         // [N]
    float* z0    = sv + NN;                               // [N]
    float* z1    = z0 + NN;                               // [N]
    float* u     = z1 + NN;                               // [64]
    int*   rowptrp = (int*)(u + 64);                      // [N] packed
    int*   gcur  = rowptrp + NN;                          // [512]
    int*   pairs = gcur + 512;                            // [(NBK+1)*CAPQ]
    int*   esrc  = pairs + (size_t)(NBK + 1) * CAPQ;      // [NBK*CAPE]

    const int T = 256;

    // ---- CSR build (histogram-free, bucketed) ----
    k_init<<<3, T, 0, stream>>>(gcur, A16, B16, h1p16, g1p16, dinv);
    k_part<<<512, T, 0, stream>>>((const int4*)ei, (const int4*)(ei + NE),
                                  gcur, pairs, NE / 4);
    k_bucket<<<NBK, T, 0, stream>>>(pairs, gcur, esrc, rowptrp, dinv, NN);

    // ---- precombined layer-2+head weights + out init ----
    k_comb<<<9, T, 0, stream>>>(w2i, w2w, w2r, w2b, wg, bg, u, out);

    // ---- layer 1 input transforms ----
    k_mmAR<<<2048, T, 0, stream>>>(x, w1i, w1r, w1b, dinv, (ushort4*)A16, (float4*)R, NN);

    // t=0: B16 = bf16( dinv * relu(prop(A16) + R) * dinv ); also sv
    k_prop48<1, 1, 1><<<cdiv((long long)NN * 6, T), T, 0, stream>>>(
        A16, (const float4*)R, rowptrp, esrc, dinv, sv, B16, NN);
    // t=1 agg: A16 = bf16( dinv * prop(B16) )
    k_prop48<0, 0, 0><<<cdiv((long long)NN * 6, T), T, 0, stream>>>(
        B16, nullptr, rowptrp, esrc, dinv, nullptr, A16, NN);
    // h1p16 = bf16(dinv * mean_k relu(A@w1w + R)); z0 = h1.u0
    k_post1<<<cdiv((long long)NN * 4, T), T, 0, stream>>>(
        A16, (const float4*)R, w1w, dinv, u, (ushort4*)h1p16, z0, NN);

    // ---- layer 2 (linearized): g1p16 + z1, then fused g2+score+pool ----
    k_prop16z<<<cdiv((long long)NN * 8, T), T, 0, stream>>>(
        h1p16, rowptrp, esrc, dinv, u, g1p16, z1, NN);
    k_score<<<cdiv((long long)NN * 8, T), T, 0, stream>>>(
        g1p16, rowptrp, esrc, dinv, u, z0, z1, sv, batch, out, NN);
}

// Round 12
// 202.997 us; speedup vs baseline: 1.0510x; 1.0510x over previous
//
#include <hip/hip_runtime.h>

#define NN 100000
#define NE 1200000
#define NG 2048
#define NBK 391           // cdiv(NN,256) buckets of 256 nodes
#define CAPQ 4096         // raw records capacity per bucket (mean 3070, >18 sigma)
#define CAPE 5120         // padded CSR capacity per bucket

static inline int cdiv(long long a, int b) { return (int)((a + b - 1) / b); }

// ---------------- bf16 helpers (RNE pack, shift unpack) ----------------
__device__ __forceinline__ unsigned short f2bf(float f) {
    unsigned int u = __float_as_uint(f);
    u += 0x7fffu + ((u >> 16) & 1u);
    return (unsigned short)(u >> 16);
}
__device__ __forceinline__ unsigned int pack2(float a, float b) {
    return (unsigned int)f2bf(a) | ((unsigned int)f2bf(b) << 16);
}
__device__ __forceinline__ float lo2f(unsigned int w) { return __uint_as_float(w << 16); }
__device__ __forceinline__ float hi2f(unsigned int w) { return __uint_as_float(w & 0xffff0000u); }

// ---------------- init: bucket cursors + sentinel rows/scalars ----------------
__global__ void k_init(int* __restrict__ gcur, uint4* __restrict__ A16,
                       uint4* __restrict__ B16, float2* __restrict__ s12,
                       float* __restrict__ t2, float* __restrict__ dinv) {
    int g = blockIdx.x * blockDim.x + threadIdx.x;
    if (g < NBK) gcur[g] = g * CAPQ;
    if (g == NBK) dinv[NN] = 0.f;
    if (g == NBK + 1) s12[NN] = make_float2(0.f, 0.f);
    if (g == NBK + 2) t2[NN] = 0.f;
    uint4 z = make_uint4(0u, 0u, 0u, 0u);
    int s = g - 512;
    if (s >= 0 && s < 6) {
        A16[(size_t)NN * 6 + s] = z;
        B16[(size_t)NN * 6 + s] = z;
    }
}

// ---------------- phase 1: partition edges bucket-major into pairs (int4, 512 blocks) ----------------
__global__ __launch_bounds__(256) void k_part(const int4* __restrict__ row4,
                                              const int4* __restrict__ col4,
                                              int* __restrict__ gcur,
                                              int* __restrict__ pairs, int E4) {
    __shared__ int hcnt[NBK];
    __shared__ int hbase[NBK];
    int chunk = (E4 + gridDim.x - 1) / gridDim.x;
    int beg = blockIdx.x * chunk;
    int end = min(E4, beg + chunk);
    for (int j = threadIdx.x; j < NBK; j += 256) hcnt[j] = 0;
    __syncthreads();
    for (int g = beg + threadIdx.x; g < end; g += 256) {
        int4 c = col4[g];
        atomicAdd(&hcnt[c.x >> 8], 1);
        atomicAdd(&hcnt[c.y >> 8], 1);
        atomicAdd(&hcnt[c.z >> 8], 1);
        atomicAdd(&hcnt[c.w >> 8], 1);
    }
    __syncthreads();
    for (int j = threadIdx.x; j < NBK; j += 256) {
        int c = hcnt[j];
        hbase[j] = c > 0 ? atomicAdd(&gcur[j], c) : 0;
        hcnt[j] = 0;
    }
    __syncthreads();
    for (int g = beg + threadIdx.x; g < end; g += 256) {
        int4 c = col4[g];
        int4 r = row4[g];
        int b0 = c.x >> 8, b1 = c.y >> 8, b2 = c.z >> 8, b3 = c.w >> 8;
        int p0 = hbase[b0] + atomicAdd(&hcnt[b0], 1);
        if (p0 < (b0 + 1) * CAPQ) pairs[p0] = ((c.x & 255) << 17) | r.x;
        int p1 = hbase[b1] + atomicAdd(&hcnt[b1], 1);
        if (p1 < (b1 + 1) * CAPQ) pairs[p1] = ((c.y & 255) << 17) | r.y;
        int p2 = hbase[b2] + atomicAdd(&hcnt[b2], 1);
        if (p2 < (b2 + 1) * CAPQ) pairs[p2] = ((c.z & 255) << 17) | r.z;
        int p3 = hbase[b3] + atomicAdd(&hcnt[b3], 1);
        if (p3 < (b3 + 1) * CAPQ) pairs[p3] = ((c.w & 255) << 17) | r.w;
    }
}

// ---------------- phase 2: per-bucket count/scan/dinv/rowptr + staged scatter (int4) ----------------
// packed rowptr: bits[0:20) = beg>>2, bits[20:31) = paddedCount>>2
__global__ __launch_bounds__(256) void k_bucket(const int* __restrict__ pairs,
                                                const int* __restrict__ gcur,
                                                int* __restrict__ esrc,
                                                int* __restrict__ rowptrp,
                                                float* __restrict__ dinv, int N) {
    __shared__ int stage[CAPE];
    __shared__ int lcnt[256];
    __shared__ int s[256];
    __shared__ int tot;
    int b = blockIdx.x;
    int base = b << 8;
    int nn = min(256, N - base);
    int qb = b * CAPQ;
    int qe = min(gcur[b], qb + CAPQ);
    int cnt = qe - qb;
    int n4 = cnt >> 2, tail = cnt & 3;
    const int4* pairs4 = (const int4*)(pairs + qb);
    int tid = threadIdx.x;
    lcnt[tid] = 0;
    __syncthreads();
    for (int g = tid; g < n4; g += 256) {
        int4 v = pairs4[g];
        atomicAdd(&lcnt[v.x >> 17], 1);
        atomicAdd(&lcnt[v.y >> 17], 1);
        atomicAdd(&lcnt[v.z >> 17], 1);
        atomicAdd(&lcnt[v.w >> 17], 1);
    }
    if (tid < tail) atomicAdd(&lcnt[pairs[qb + n4 * 4 + tid] >> 17], 1);
    __syncthreads();
    int c = lcnt[tid];
    int pc = (c + 3) & ~3;
    s[tid] = pc;
    __syncthreads();
    for (int off = 1; off < 256; off <<= 1) {
        int t = (tid >= off) ? s[tid - off] : 0;
        __syncthreads();
        s[tid] += t;
        __syncthreads();
    }
    int myofs = s[tid] - pc;
    if (tid == 255) tot = s[255];
    __syncthreads();
    int padded = tot;
    if (tid < nn) {
        dinv[base + tid] = c > 0 ? rsqrtf((float)c) : 0.f;
        rowptrp[base + tid] = ((b * CAPE + myofs) >> 2) | ((pc >> 2) << 20);
    }
    int4* stage4 = (int4*)stage;
    int pad4 = padded >> 2;
    int4 sent = make_int4(N, N, N, N);
    for (int i = tid; i < pad4; i += 256) stage4[i] = sent;
    lcnt[tid] = myofs;
    __syncthreads();
    for (int g = tid; g < n4; g += 256) {
        int4 v = pairs4[g];
        int pos;
        pos = atomicAdd(&lcnt[v.x >> 17], 1); stage[pos] = v.x & 0x1FFFF;
        pos = atomicAdd(&lcnt[v.y >> 17], 1); stage[pos] = v.y & 0x1FFFF;
        pos = atomicAdd(&lcnt[v.z >> 17], 1); stage[pos] = v.z & 0x1FFFF;
        pos = atomicAdd(&lcnt[v.w >> 17], 1); stage[pos] = v.w & 0x1FFFF;
    }
    if (tid < tail) {
        int v = pairs[qb + n4 * 4 + tid];
        int pos = atomicAdd(&lcnt[v >> 17], 1);
        stage[pos] = v & 0x1FFFF;
    }
    __syncthreads();
    int4* esrc4 = (int4*)(esrc + b * CAPE);
    for (int i = tid; i < pad4; i += 256) esrc4[i] = stage4[i];
}

// ---------------- fused layer-1 transforms: A16=(x@w1i)*dinv (bf16), R=x@w1r+b (fp32) ----------------
__global__ void k_mmAR(const float* __restrict__ x,
                       const float* __restrict__ w1i, const float* __restrict__ w1r,
                       const float* __restrict__ b1, const float* __restrict__ dinv,
                       ushort4* __restrict__ A16s, float4* __restrict__ R4, int N) {
    __shared__ float4 Wi[900];   // [3][75][4] float4
    __shared__ float4 Wr[900];
    __shared__ float4 Bs[12];
    const float4* wi4 = (const float4*)w1i;
    const float4* wr4 = (const float4*)w1r;
    for (int i = threadIdx.x; i < 900; i += blockDim.x) { Wi[i] = wi4[i]; Wr[i] = wr4[i]; }
    if (threadIdx.x < 12) Bs[threadIdx.x] = ((const float4*)b1)[threadIdx.x];
    __syncthreads();
    const int total = N * 12;
    const int stride = gridDim.x * blockDim.x;
    for (int idx = blockIdx.x * blockDim.x + threadIdx.x; idx < total; idx += stride) {
        int n = idx / 12;
        int q = idx - n * 12;
        int k = q >> 2, o4 = q & 3;
        const float* xp = x + (size_t)n * 75;
        const float4* wpi = Wi + (k * 75) * 4 + o4;
        const float4* wpr = Wr + (k * 75) * 4 + o4;
        float aix = 0.f, aiy = 0.f, aiz = 0.f, aiw = 0.f;
        float4 br = Bs[q];
        float arx = br.x, ary = br.y, arz = br.z, arw = br.w;
#pragma unroll
        for (int f = 0; f < 75; ++f) {
            float xv = xp[f];
            float4 wi = wpi[f * 4];
            float4 wr = wpr[f * 4];
            aix = fmaf(xv, wi.x, aix);
            aiy = fmaf(xv, wi.y, aiy);
            aiz = fmaf(xv, wi.z, aiz);
            aiw = fmaf(xv, wi.w, aiw);
            arx = fmaf(xv, wr.x, arx);
            ary = fmaf(xv, wr.y, ary);
            arz = fmaf(xv, wr.z, arz);
            arw = fmaf(xv, wr.w, arw);
        }
        float dn = dinv[n];
        ushort4 sa;
        sa.x = f2bf(aix * dn); sa.y = f2bf(aiy * dn);
        sa.z = f2bf(aiz * dn); sa.w = f2bf(aiw * dn);
        A16s[(size_t)n * 12 + q] = sa;
        R4[idx] = make_float4(arx, ary, arz, arw);
    }
}

// ---------------- 48-wide CSR prop over bf16 rows (6 threads/node, 2x edge unroll) ----------------
#define ACC8(W)                                                     \
    a0 += lo2f(W.x); a1 += hi2f(W.x); a2 += lo2f(W.y); a3 += hi2f(W.y); \
    a4 += lo2f(W.z); a5 += hi2f(W.z); a6 += lo2f(W.w); a7 += hi2f(W.w);

template <int HAS_R, int COMPUTE_S, int SCALE_OUT>
__global__ void k_prop48(const uint4* __restrict__ src, const float4* __restrict__ R4,
                         const int* __restrict__ rowptrp, const int* __restrict__ esrc,
                         const float* __restrict__ dinv, float* __restrict__ sv,
                         uint4* __restrict__ dst, int N) {
    const int total = N * 6;
    const int stride = gridDim.x * blockDim.x;
    for (int idx = blockIdx.x * blockDim.x + threadIdx.x; idx < total; idx += stride) {
        int n = idx / 6;
        int q = idx - n * 6;
        int rp = rowptrp[n];
        int beg = (rp & 0xFFFFF) << 2;
        int end = beg + ((rp >> 20) << 2);
        float a0 = 0.f, a1 = 0.f, a2 = 0.f, a3 = 0.f, a4 = 0.f, a5 = 0.f, a6 = 0.f, a7 = 0.f;
        float sd = 0.f;
        int p = beg;
        for (; p + 8 <= end; p += 8) {
            int4 e0 = *(const int4*)(esrc + p);
            int4 e1 = *(const int4*)(esrc + p + 4);
            uint4 w0 = src[(size_t)e0.x * 6 + q];
            uint4 w1 = src[(size_t)e0.y * 6 + q];
            uint4 w2 = src[(size_t)e0.z * 6 + q];
            uint4 w3 = src[(size_t)e0.w * 6 + q];
            uint4 w4 = src[(size_t)e1.x * 6 + q];
            uint4 w5 = src[(size_t)e1.y * 6 + q];
            uint4 w6 = src[(size_t)e1.z * 6 + q];
            uint4 w7 = src[(size_t)e1.w * 6 + q];
            ACC8(w0); ACC8(w1); ACC8(w2); ACC8(w3);
            ACC8(w4); ACC8(w5); ACC8(w6); ACC8(w7);
            if (COMPUTE_S) {
                if (q == 0)
                    sd += ((dinv[e0.x] + dinv[e0.y]) + (dinv[e0.z] + dinv[e0.w]))
                        + ((dinv[e1.x] + dinv[e1.y]) + (dinv[e1.z] + dinv[e1.w]));
            }
        }
        if (p < end) {
            int4 e = *(const int4*)(esrc + p);
            uint4 w0 = src[(size_t)e.x * 6 + q];
            uint4 w1 = src[(size_t)e.y * 6 + q];
            uint4 w2 = src[(size_t)e.z * 6 + q];
            uint4 w3 = src[(size_t)e.w * 6 + q];
            ACC8(w0); ACC8(w1); ACC8(w2); ACC8(w3);
            if (COMPUTE_S) {
                if (q == 0)
                    sd += (dinv[e.x] + dinv[e.y]) + (dinv[e.z] + dinv[e.w]);
            }
        }
        float dn = dinv[n];
        float v0 = a0 * dn, v1 = a1 * dn, v2 = a2 * dn, v3 = a3 * dn;
        float v4 = a4 * dn, v5 = a5 * dn, v6 = a6 * dn, v7 = a7 * dn;
        if (HAS_R) {
            float4 r0 = R4[(size_t)n * 12 + q * 2];
            float4 r1 = R4[(size_t)n * 12 + q * 2 + 1];
            v0 = fmaxf(v0 + r0.x, 0.f); v1 = fmaxf(v1 + r0.y, 0.f);
            v2 = fmaxf(v2 + r0.z, 0.f); v3 = fmaxf(v3 + r0.w, 0.f);
            v4 = fmaxf(v4 + r1.x, 0.f); v5 = fmaxf(v5 + r1.y, 0.f);
            v6 = fmaxf(v6 + r1.z, 0.f); v7 = fmaxf(v7 + r1.w, 0.f);
        }
        if (SCALE_OUT) {
            v0 *= dn; v1 *= dn; v2 *= dn; v3 *= dn;
            v4 *= dn; v5 *= dn; v6 *= dn; v7 *= dn;
        }
        uint4 o;
        o.x = pack2(v0, v1); o.y = pack2(v2, v3);
        o.z = pack2(v4, v5); o.w = pack2(v6, v7);
        dst[(size_t)n * 6 + q] = o;
        if (COMPUTE_S) {
            if (q == 0) sv[n] = sd * dn;
        }
    }
}

// ---------------- layer-1 t=1 epilogue: h1 = mean_k relu(A@w1w+R) -> z0, (s1,s2) scalars ----------------
// s1 = (h1*dinv)·u1, s2 = (h1*dinv)·u2 ; h1 itself never materialized
__global__ void k_post1(const uint4* __restrict__ A16, const float4* __restrict__ R4,
                        const float* __restrict__ w1w, const float* __restrict__ dinv,
                        const float* __restrict__ u,
                        float* __restrict__ z0, float2* __restrict__ s12, int N) {
    __shared__ float4 Ws[192];  // [3][16][4] float4 of w1w[k][i][o]
    const float4* w4 = (const float4*)w1w;
    for (int i = threadIdx.x; i < 192; i += blockDim.x) Ws[i] = w4[i];
    __syncthreads();
    const int total = N * 4;
    const int stride = gridDim.x * blockDim.x;
    for (int idx = blockIdx.x * blockDim.x + threadIdx.x; idx < total; idx += stride) {
        int n = idx >> 2;
        int o4 = idx & 3;
        const uint4* ap = A16 + (size_t)n * 6;
        float av[48];
#pragma unroll
        for (int c6 = 0; c6 < 6; ++c6) {
            uint4 w = ap[c6];
            av[c6 * 8 + 0] = lo2f(w.x); av[c6 * 8 + 1] = hi2f(w.x);
            av[c6 * 8 + 2] = lo2f(w.y); av[c6 * 8 + 3] = hi2f(w.y);
            av[c6 * 8 + 4] = lo2f(w.z); av[c6 * 8 + 5] = hi2f(w.z);
            av[c6 * 8 + 6] = lo2f(w.w); av[c6 * 8 + 7] = hi2f(w.w);
        }
        float4 sum = make_float4(0.f, 0.f, 0.f, 0.f);
#pragma unroll
        for (int k = 0; k < 3; ++k) {
            float4 d = R4[(size_t)n * 12 + k * 4 + o4];
#pragma unroll
            for (int i = 0; i < 16; ++i) {
                float a = av[k * 16 + i];
                float4 w = Ws[(k * 16 + i) * 4 + o4];
                d.x = fmaf(a, w.x, d.x);
                d.y = fmaf(a, w.y, d.y);
                d.z = fmaf(a, w.z, d.z);
                d.w = fmaf(a, w.w, d.w);
            }
            d.x = fmaxf(d.x, 0.f); d.y = fmaxf(d.y, 0.f);
            d.z = fmaxf(d.z, 0.f); d.w = fmaxf(d.w, 0.f);
            sum.x += d.x; sum.y += d.y; sum.z += d.z; sum.w += d.w;
        }
        const float third = 1.0f / 3.0f;
        sum.x *= third; sum.y *= third; sum.z *= third; sum.w *= third;
        float4 u0q = ((const float4*)u)[o4];
        float4 u1q = ((const float4*)u)[4 + o4];
        float4 u2q = ((const float4*)u)[8 + o4];
        float d0 = sum.x * u0q.x + sum.y * u0q.y + sum.z * u0q.z + sum.w * u0q.w;
        float d1 = sum.x * u1q.x + sum.y * u1q.y + sum.z * u1q.z + sum.w * u1q.w;
        float d2 = sum.x * u2q.x + sum.y * u2q.y + sum.z * u2q.z + sum.w * u2q.w;
        d0 += __shfl_down(d0, 2, 4); d0 += __shfl_down(d0, 1, 4);
        d1 += __shfl_down(d1, 2, 4); d1 += __shfl_down(d1, 1, 4);
        d2 += __shfl_down(d2, 2, 4); d2 += __shfl_down(d2, 1, 4);
        if (o4 == 0) {
            float dn = dinv[n];
            z0[n] = d0;
            s12[n] = make_float2(d1 * dn, d2 * dn);
        }
    }
}

// ---------------- pass A: scalar prop of (s1,s2): z01 = z0 + dinv*Σs1 ; t2 = dinv²*Σs2 ----------------
__global__ void k_passA(const float2* __restrict__ s12,
                        const int* __restrict__ rowptrp, const int* __restrict__ esrc,
                        const float* __restrict__ dinv, const float* __restrict__ z0,
                        float* __restrict__ z01, float* __restrict__ t2, int N) {
    int n = blockIdx.x * blockDim.x + threadIdx.x;
    if (n >= N) return;
    int rp = rowptrp[n];
    int beg = (rp & 0xFFFFF) << 2;
    int end = beg + ((rp >> 20) << 2);
    float S1 = 0.f, S2 = 0.f;
    int p = beg;
    for (; p + 8 <= end; p += 8) {
        int4 e0 = *(const int4*)(esrc + p);
        int4 e1 = *(const int4*)(esrc + p + 4);
        float2 v0 = s12[e0.x], v1 = s12[e0.y], v2 = s12[e0.z], v3 = s12[e0.w];
        float2 v4 = s12[e1.x], v5 = s12[e1.y], v6 = s12[e1.z], v7 = s12[e1.w];
        S1 += ((v0.x + v1.x) + (v2.x + v3.x)) + ((v4.x + v5.x) + (v6.x + v7.x));
        S2 += ((v0.y + v1.y) + (v2.y + v3.y)) + ((v4.y + v5.y) + (v6.y + v7.y));
    }
    if (p < end) {
        int4 e = *(const int4*)(esrc + p);
        float2 v0 = s12[e.x], v1 = s12[e.y], v2 = s12[e.z], v3 = s12[e.w];
        S1 += (v0.x + v1.x) + (v2.x + v3.x);
        S2 += (v0.y + v1.y) + (v2.y + v3.y);
    }
    float dn = dinv[n];
    z01[n] = z0[n] + dn * S1;
    t2[n] = dn * dn * S2;
}

// ---------------- pass B: scalar prop of t2 + final score + pool ----------------
__global__ void k_passB(const float* __restrict__ t2,
                        const int* __restrict__ rowptrp, const int* __restrict__ esrc,
                        const float* __restrict__ dinv, const float* __restrict__ z01,
                        const float* __restrict__ sv, const float* __restrict__ u,
                        const int* __restrict__ batch, float* __restrict__ out, int N) {
    int n = blockIdx.x * blockDim.x + threadIdx.x;
    if (n >= N) return;
    int rp = rowptrp[n];
    int beg = (rp & 0xFFFFF) << 2;
    int end = beg + ((rp >> 20) << 2);
    float S = 0.f;
    int p = beg;
    for (; p + 8 <= end; p += 8) {
        int4 e0 = *(const int4*)(esrc + p);
        int4 e1 = *(const int4*)(esrc + p + 4);
        S += ((t2[e0.x] + t2[e0.y]) + (t2[e0.z] + t2[e0.w]))
           + ((t2[e1.x] + t2[e1.y]) + (t2[e1.z] + t2[e1.w]));
    }
    if (p < end) {
        int4 e = *(const int4*)(esrc + p);
        S += (t2[e.x] + t2[e.y]) + (t2[e.z] + t2[e.w]);
    }
    float v = z01[n] + dinv[n] * S + sv[n] * u[48] + u[49];
    atomicAdd(&out[batch[n]], v);
}

// ---------------- precombine layer-2+head weights; blocks 1..8 init out ----------------
__global__ void k_comb(const float* __restrict__ w2i, const float* __restrict__ w2w,
                       const float* __restrict__ w2r, const float* __restrict__ b2,
                       const float* __restrict__ wg, const float* __restrict__ bg,
                       float* __restrict__ u, float* __restrict__ out) {
    if (blockIdx.x > 0) {
        int g = (blockIdx.x - 1) * 256 + threadIdx.x;
        if (g < NG) out[g] = bg[0];
        return;
    }
    __shared__ float t[3][64];
    int tid = threadIdx.x;
    if (tid < 64) {
#pragma unroll
        for (int k = 0; k < 3; ++k) {
            float a = 0.f;
            for (int j = 0; j < 64; ++j) a = fmaf(w2w[k * 4096 + tid * 64 + j], wg[j], a);
            t[k][tid] = a;
        }
    }
    __syncthreads();
    if (tid < 64) {
        float wgv = wg[tid];
        float tk0 = t[0][tid], tk1 = t[1][tid], tk2 = t[2][tid];
        const float third = 1.0f / 3.0f;
        for (int j = 0; j < 16; ++j) {
            float wi0 = w2i[j * 64 + tid], wi1 = w2i[1024 + j * 64 + tid], wi2 = w2i[2048 + j * 64 + tid];
            float wr0 = w2r[j * 64 + tid], wr1 = w2r[1024 + j * 64 + tid], wr2 = w2r[2048 + j * 64 + tid];
            float a2 = wi0 * tk0 + wi1 * tk1 + wi2 * tk2;
            float a1 = wr0 * tk0 + wr1 * tk1 + wr2 * tk2;
            float a0 = (wr0 + wr1 + wr2) * wgv;
#pragma unroll
            for (int off = 32; off > 0; off >>= 1) {
                a2 += __shfl_down(a2, off, 64);
                a1 += __shfl_down(a1, off, 64);
                a0 += __shfl_down(a0, off, 64);
            }
            if (tid == 0) {
                u[j] = a0 * third;
                u[16 + j] = a1 * third;
                u[32 + j] = a2 * third;
            }
        }
        float b0 = b2[tid], b1v = b2[64 + tid], b2v = b2[128 + tid];
        float c0 = b0 * tk0 + b1v * tk1 + b2v * tk2;
        float c1 = (b0 + b1v + b2v) * wgv;
#pragma unroll
        for (int off = 32; off > 0; off >>= 1) {
            c0 += __shfl_down(c0, off, 64);
            c1 += __shfl_down(c1, off, 64);
        }
        if (tid == 0) {
            u[48] = c0 * third;
            u[49] = c1 * third;
        }
    }
}

extern "C" void kernel_launch(void* const* d_in, const int* in_sizes, int n_in,
                              void* d_out, int out_size, void* d_ws, size_t ws_size,
                              hipStream_t stream) {
    const float* x   = (const float*)d_in[0];
    const int*   ei  = (const int*)d_in[1];
    const int*   batch = (const int*)d_in[2];
    const float* w1i = (const float*)d_in[3];
    const float* w1w = (const float*)d_in[4];
    const float* w1r = (const float*)d_in[5];
    const float* w1b = (const float*)d_in[6];
    const float* w2i = (const float*)d_in[7];
    const float* w2w = (const float*)d_in[8];
    const float* w2r = (const float*)d_in[9];
    const float* w2b = (const float*)d_in[10];
    const float* wg  = (const float*)d_in[11];
    const float* bg  = (const float*)d_in[12];
    float* out = (float*)d_out;

    // workspace layout (all 16B-aligned)
    uint4*  A16  = (uint4*)d_ws;                          // [(N+1)*6] uint4 = bf16[N+1][48]
    uint4*  B16  = A16 + (size_t)(NN + 1) * 6;            // same
    float*  R    = (float*)(B16 + (size_t)(NN + 1) * 6);  // fp32 [N][48]
    float2* s12  = (float2*)(R + (size_t)NN * 48);        // [N+1] (s1,s2)
    float*  t2   = (float*)(s12 + NN + 1);                // [N+1]
    float*  z0   = t2 + NN + 1;                           // [N]
    float*  z01  = z0 + NN;                               // [N]
    float*  dinv = z01 + NN;                              // [N+1]
    float*  sv   = dinv + NN + 1;                         // [N]
    float*  u    = sv + NN;                               // [64]
    int* rowptrp = (int*)(u + 64);                        // [N] packed
    int* gcur    = rowptrp + NN;                          // [512]
    int* pairs   = gcur + 512;                            // [(NBK+1)*CAPQ]
    int* esrc    = pairs + (size_t)(NBK + 1) * CAPQ;      // [NBK*CAPE]

    const int T = 256;

    // ---- CSR build (histogram-free, bucketed) ----
    k_init<<<3, T, 0, stream>>>(gcur, A16, B16, s12, t2, dinv);
    k_part<<<512, T, 0, stream>>>((const int4*)ei, (const int4*)(ei + NE),
                                  gcur, pairs, NE / 4);
    k_bucket<<<NBK, T, 0, stream>>>(pairs, gcur, esrc, rowptrp, dinv, NN);

    // ---- precombined layer-2+head weights + out init ----
    k_comb<<<9, T, 0, stream>>>(w2i, w2w, w2r, w2b, wg, bg, u, out);

    // ---- layer 1 input transforms ----
    k_mmAR<<<2048, T, 0, stream>>>(x, w1i, w1r, w1b, dinv, (ushort4*)A16, (float4*)R, NN);

    // t=0: B16 = bf16( dinv * relu(prop(A16) + R) * dinv ); also sv
    k_prop48<1, 1, 1><<<cdiv((long long)NN * 6, T), T, 0, stream>>>(
        A16, (const float4*)R, rowptrp, esrc, dinv, sv, B16, NN);
    // t=1 agg: A16 = bf16( dinv * prop(B16) )
    k_prop48<0, 0, 0><<<cdiv((long long)NN * 6, T), T, 0, stream>>>(
        B16, nullptr, rowptrp, esrc, dinv, nullptr, A16, NN);
    // z0 = h1·u0 ; s12 = ((h1 dinv)·u1, (h1 dinv)·u2)
    k_post1<<<cdiv((long long)NN * 4, T), T, 0, stream>>>(
        A16, (const float4*)R, w1w, dinv, u, z0, s12, NN);

    // ---- layer 2, fully scalarized: two scalar-gather passes ----
    k_passA<<<cdiv(NN, T), T, 0, stream>>>(s12, rowptrp, esrc, dinv, z0, z01, t2, NN);
    k_passB<<<cdiv(NN, T), T, 0, stream>>>(t2, rowptrp, esrc, dinv, z01, sv, u, batch, out, NN);
}

// Round 13
// 193.534 us; speedup vs baseline: 1.1024x; 1.0489x over previous
//
#include <hip/hip_runtime.h>

#define NN 100000
#define NE 1200000
#define NG 2048
#define NBK 391           // cdiv(NN,256) buckets of 256 nodes
#define CAPQ 4096         // raw records capacity per bucket (mean 3070, >18 sigma)
#define CAPE 5120         // padded CSR capacity per bucket
#define NPB 42            // nodes per block in fused prop+post kernel

static inline int cdiv(long long a, int b) { return (int)((a + b - 1) / b); }

// ---------------- bf16 helpers (RNE pack, shift unpack) ----------------
__device__ __forceinline__ unsigned short f2bf(float f) {
    unsigned int u = __float_as_uint(f);
    u += 0x7fffu + ((u >> 16) & 1u);
    return (unsigned short)(u >> 16);
}
__device__ __forceinline__ float bf2f(unsigned short h) {
    return __uint_as_float((unsigned int)h << 16);
}
__device__ __forceinline__ float lo2f(unsigned int w) { return __uint_as_float(w << 16); }
__device__ __forceinline__ float hi2f(unsigned int w) { return __uint_as_float(w & 0xffff0000u); }

// ---------------- init: bucket cursors + sentinel rows/scalars ----------------
__global__ void k_init(int* __restrict__ gcur, uint4* __restrict__ A16,
                       uint4* __restrict__ B16, float2* __restrict__ s12,
                       float* __restrict__ t2, float* __restrict__ dinv) {
    int g = blockIdx.x * blockDim.x + threadIdx.x;
    if (g < NBK) gcur[g] = g * CAPQ;
    if (g == NBK) dinv[NN] = 0.f;
    if (g == NBK + 1) s12[NN] = make_float2(0.f, 0.f);
    if (g == NBK + 2) t2[NN] = 0.f;
    uint4 z = make_uint4(0u, 0u, 0u, 0u);
    int s = g - 512;
    if (s >= 0 && s < 6) {
        A16[(size_t)NN * 6 + s] = z;
        B16[(size_t)NN * 6 + s] = z;
    }
}

// ---------------- phase 1: partition edges bucket-major into pairs ----------------
__global__ __launch_bounds__(256) void k_part(const int4* __restrict__ row4,
                                              const int4* __restrict__ col4,
                                              int* __restrict__ gcur,
                                              int* __restrict__ pairs, int E4) {
    __shared__ int hcnt[NBK];
    __shared__ int hbase[NBK];
    int chunk = (E4 + gridDim.x - 1) / gridDim.x;
    int beg = blockIdx.x * chunk;
    int end = min(E4, beg + chunk);
    for (int j = threadIdx.x; j < NBK; j += 256) hcnt[j] = 0;
    __syncthreads();
    for (int g = beg + threadIdx.x; g < end; g += 256) {
        int4 c = col4[g];
        atomicAdd(&hcnt[c.x >> 8], 1);
        atomicAdd(&hcnt[c.y >> 8], 1);
        atomicAdd(&hcnt[c.z >> 8], 1);
        atomicAdd(&hcnt[c.w >> 8], 1);
    }
    __syncthreads();
    for (int j = threadIdx.x; j < NBK; j += 256) {
        int c = hcnt[j];
        hbase[j] = c > 0 ? atomicAdd(&gcur[j], c) : 0;
        hcnt[j] = 0;
    }
    __syncthreads();
    for (int g = beg + threadIdx.x; g < end; g += 256) {
        int4 c = col4[g];
        int4 r = row4[g];
        int b0 = c.x >> 8, b1 = c.y >> 8, b2 = c.z >> 8, b3 = c.w >> 8;
        int p0 = hbase[b0] + atomicAdd(&hcnt[b0], 1);
        if (p0 < (b0 + 1) * CAPQ) pairs[p0] = ((c.x & 255) << 17) | r.x;
        int p1 = hbase[b1] + atomicAdd(&hcnt[b1], 1);
        if (p1 < (b1 + 1) * CAPQ) pairs[p1] = ((c.y & 255) << 17) | r.y;
        int p2 = hbase[b2] + atomicAdd(&hcnt[b2], 1);
        if (p2 < (b2 + 1) * CAPQ) pairs[p2] = ((c.z & 255) << 17) | r.z;
        int p3 = hbase[b3] + atomicAdd(&hcnt[b3], 1);
        if (p3 < (b3 + 1) * CAPQ) pairs[p3] = ((c.w & 255) << 17) | r.w;
    }
}

// ---------------- phase 2: per-bucket count/scan/dinv/rowptr + staged scatter ----------------
__global__ __launch_bounds__(256) void k_bucket(const int* __restrict__ pairs,
                                                const int* __restrict__ gcur,
                                                int* __restrict__ esrc,
                                                int* __restrict__ rowptrp,
                                                float* __restrict__ dinv, int N) {
    __shared__ int stage[CAPE];
    __shared__ int lcnt[256];
    __shared__ int s[256];
    __shared__ int tot;
    int b = blockIdx.x;
    int base = b << 8;
    int nn = min(256, N - base);
    int qb = b * CAPQ;
    int qe = min(gcur[b], qb + CAPQ);
    int cnt = qe - qb;
    int n4 = cnt >> 2, tail = cnt & 3;
    const int4* pairs4 = (const int4*)(pairs + qb);
    int tid = threadIdx.x;
    lcnt[tid] = 0;
    __syncthreads();
    for (int g = tid; g < n4; g += 256) {
        int4 v = pairs4[g];
        atomicAdd(&lcnt[v.x >> 17], 1);
        atomicAdd(&lcnt[v.y >> 17], 1);
        atomicAdd(&lcnt[v.z >> 17], 1);
        atomicAdd(&lcnt[v.w >> 17], 1);
    }
    if (tid < tail) atomicAdd(&lcnt[pairs[qb + n4 * 4 + tid] >> 17], 1);
    __syncthreads();
    int c = lcnt[tid];
    int pc = (c + 3) & ~3;
    s[tid] = pc;
    __syncthreads();
    for (int off = 1; off < 256; off <<= 1) {
        int t = (tid >= off) ? s[tid - off] : 0;
        __syncthreads();
        s[tid] += t;
        __syncthreads();
    }
    int myofs = s[tid] - pc;
    if (tid == 255) tot = s[255];
    __syncthreads();
    int padded = tot;
    if (tid < nn) {
        dinv[base + tid] = c > 0 ? rsqrtf((float)c) : 0.f;
        rowptrp[base + tid] = ((b * CAPE + myofs) >> 2) | ((pc >> 2) << 20);
    }
    int4* stage4 = (int4*)stage;
    int pad4 = padded >> 2;
    int4 sent = make_int4(N, N, N, N);
    for (int i = tid; i < pad4; i += 256) stage4[i] = sent;
    lcnt[tid] = myofs;
    __syncthreads();
    for (int g = tid; g < n4; g += 256) {
        int4 v = pairs4[g];
        int pos;
        pos = atomicAdd(&lcnt[v.x >> 17], 1); stage[pos] = v.x & 0x1FFFF;
        pos = atomicAdd(&lcnt[v.y >> 17], 1); stage[pos] = v.y & 0x1FFFF;
        pos = atomicAdd(&lcnt[v.z >> 17], 1); stage[pos] = v.z & 0x1FFFF;
        pos = atomicAdd(&lcnt[v.w >> 17], 1); stage[pos] = v.w & 0x1FFFF;
    }
    if (tid < tail) {
        int v = pairs[qb + n4 * 4 + tid];
        int pos = atomicAdd(&lcnt[v >> 17], 1);
        stage[pos] = v & 0x1FFFF;
    }
    __syncthreads();
    int4* esrc4 = (int4*)(esrc + b * CAPE);
    for (int i = tid; i < pad4; i += 256) esrc4[i] = stage4[i];
}

// ---------------- fused layer-1 transforms: A16=(x@w1i)*dinv, R16=x@w1r+b (both bf16) ----------------
__global__ void k_mmAR(const float* __restrict__ x,
                       const float* __restrict__ w1i, const float* __restrict__ w1r,
                       const float* __restrict__ b1, const float* __restrict__ dinv,
                       ushort4* __restrict__ A16s, ushort4* __restrict__ R16s, int N) {
    __shared__ float4 Wi[900];   // [3][75][4] float4
    __shared__ float4 Wr[900];
    __shared__ float4 Bs[12];
    const float4* wi4 = (const float4*)w1i;
    const float4* wr4 = (const float4*)w1r;
    for (int i = threadIdx.x; i < 900; i += blockDim.x) { Wi[i] = wi4[i]; Wr[i] = wr4[i]; }
    if (threadIdx.x < 12) Bs[threadIdx.x] = ((const float4*)b1)[threadIdx.x];
    __syncthreads();
    const int total = N * 12;
    const int stride = gridDim.x * blockDim.x;
    for (int idx = blockIdx.x * blockDim.x + threadIdx.x; idx < total; idx += stride) {
        int n = idx / 12;
        int q = idx - n * 12;
        int k = q >> 2, o4 = q & 3;
        const float* xp = x + (size_t)n * 75;
        const float4* wpi = Wi + (k * 75) * 4 + o4;
        const float4* wpr = Wr + (k * 75) * 4 + o4;
        float aix = 0.f, aiy = 0.f, aiz = 0.f, aiw = 0.f;
        float4 br = Bs[q];
        float arx = br.x, ary = br.y, arz = br.z, arw = br.w;
#pragma unroll
        for (int f = 0; f < 75; ++f) {
            float xv = xp[f];
            float4 wi = wpi[f * 4];
            float4 wr = wpr[f * 4];
            aix = fmaf(xv, wi.x, aix);
            aiy = fmaf(xv, wi.y, aiy);
            aiz = fmaf(xv, wi.z, aiz);
            aiw = fmaf(xv, wi.w, aiw);
            arx = fmaf(xv, wr.x, arx);
            ary = fmaf(xv, wr.y, ary);
            arz = fmaf(xv, wr.z, arz);
            arw = fmaf(xv, wr.w, arw);
        }
        float dn = dinv[n];
        ushort4 sa;
        sa.x = f2bf(aix * dn); sa.y = f2bf(aiy * dn);
        sa.z = f2bf(aiz * dn); sa.w = f2bf(aiw * dn);
        A16s[(size_t)n * 12 + q] = sa;
        ushort4 sr;
        sr.x = f2bf(arx); sr.y = f2bf(ary);
        sr.z = f2bf(arz); sr.w = f2bf(arw);
        R16s[(size_t)n * 12 + q] = sr;
    }
}

// ---------------- 48-wide CSR prop t=0: B16 = bf16(dinv*relu(prop(A16)+R)*dinv); sv ----------------
#define ACC8(W)                                                     \
    a0 += lo2f(W.x); a1 += hi2f(W.x); a2 += lo2f(W.y); a3 += hi2f(W.y); \
    a4 += lo2f(W.z); a5 += hi2f(W.z); a6 += lo2f(W.w); a7 += hi2f(W.w);

__global__ void k_prop48(const uint4* __restrict__ src, const uint4* __restrict__ R16,
                         const int* __restrict__ rowptrp, const int* __restrict__ esrc,
                         const float* __restrict__ dinv, float* __restrict__ sv,
                         uint4* __restrict__ dst, int N) {
    const int total = N * 6;
    const int stride = gridDim.x * blockDim.x;
    for (int idx = blockIdx.x * blockDim.x + threadIdx.x; idx < total; idx += stride) {
        int n = idx / 6;
        int q = idx - n * 6;
        int rp = rowptrp[n];
        int beg = (rp & 0xFFFFF) << 2;
        int end = beg + ((rp >> 20) << 2);
        float a0 = 0.f, a1 = 0.f, a2 = 0.f, a3 = 0.f, a4 = 0.f, a5 = 0.f, a6 = 0.f, a7 = 0.f;
        float sd = 0.f;
        int p = beg;
        for (; p + 8 <= end; p += 8) {
            int4 e0 = *(const int4*)(esrc + p);
            int4 e1 = *(const int4*)(esrc + p + 4);
            uint4 w0 = src[(size_t)e0.x * 6 + q];
            uint4 w1 = src[(size_t)e0.y * 6 + q];
            uint4 w2 = src[(size_t)e0.z * 6 + q];
            uint4 w3 = src[(size_t)e0.w * 6 + q];
            uint4 w4 = src[(size_t)e1.x * 6 + q];
            uint4 w5 = src[(size_t)e1.y * 6 + q];
            uint4 w6 = src[(size_t)e1.z * 6 + q];
            uint4 w7 = src[(size_t)e1.w * 6 + q];
            ACC8(w0); ACC8(w1); ACC8(w2); ACC8(w3);
            ACC8(w4); ACC8(w5); ACC8(w6); ACC8(w7);
            if (q == 0)
                sd += ((dinv[e0.x] + dinv[e0.y]) + (dinv[e0.z] + dinv[e0.w]))
                    + ((dinv[e1.x] + dinv[e1.y]) + (dinv[e1.z] + dinv[e1.w]));
        }
        if (p < end) {
            int4 e = *(const int4*)(esrc + p);
            uint4 w0 = src[(size_t)e.x * 6 + q];
            uint4 w1 = src[(size_t)e.y * 6 + q];
            uint4 w2 = src[(size_t)e.z * 6 + q];
            uint4 w3 = src[(size_t)e.w * 6 + q];
            ACC8(w0); ACC8(w1); ACC8(w2); ACC8(w3);
            if (q == 0)
                sd += (dinv[e.x] + dinv[e.y]) + (dinv[e.z] + dinv[e.w]);
        }
        float dn = dinv[n];
        uint4 r = R16[(size_t)n * 6 + q];
        float v0 = fmaxf(a0 * dn + lo2f(r.x), 0.f) * dn;
        float v1 = fmaxf(a1 * dn + hi2f(r.x), 0.f) * dn;
        float v2 = fmaxf(a2 * dn + lo2f(r.y), 0.f) * dn;
        float v3 = fmaxf(a3 * dn + hi2f(r.y), 0.f) * dn;
        float v4 = fmaxf(a4 * dn + lo2f(r.z), 0.f) * dn;
        float v5 = fmaxf(a5 * dn + hi2f(r.z), 0.f) * dn;
        float v6 = fmaxf(a6 * dn + lo2f(r.w), 0.f) * dn;
        float v7 = fmaxf(a7 * dn + hi2f(r.w), 0.f) * dn;
        uint4 o;
        o.x = (unsigned)f2bf(v0) | ((unsigned)f2bf(v1) << 16);
        o.y = (unsigned)f2bf(v2) | ((unsigned)f2bf(v3) << 16);
        o.z = (unsigned)f2bf(v4) | ((unsigned)f2bf(v5) << 16);
        o.w = (unsigned)f2bf(v6) | ((unsigned)f2bf(v7) << 16);
        dst[(size_t)n * 6 + q] = o;
        if (q == 0) sv[n] = sd * dn;
    }
}

// ---------------- fused t=1 prop + post1: agg in LDS (fp32), epilogue -> z0, s12 ----------------
__global__ __launch_bounds__(256) void k_proppost(
    const uint4* __restrict__ B16, const ushort4* __restrict__ R16s,
    const float* __restrict__ w1w, const int* __restrict__ rowptrp,
    const int* __restrict__ esrc, const float* __restrict__ dinv,
    const float* __restrict__ u, float* __restrict__ z0,
    float2* __restrict__ s12, int N) {
    __shared__ float4 Ws[192];         // [3][16][4] float4 of w1w[k][i][o]
    __shared__ float ash[NPB][48];
    const float4* w4 = (const float4*)w1w;
    for (int i = threadIdx.x; i < 192; i += 256) Ws[i] = w4[i];
    int t = threadIdx.x;
    int nbase = blockIdx.x * NPB;
    if (t < NPB * 6) {
        int ln = t / 6, q = t - ln * 6;
        int n = nbase + ln;
        if (n < N) {
            int rp = rowptrp[n];
            int beg = (rp & 0xFFFFF) << 2;
            int end = beg + ((rp >> 20) << 2);
            float a0 = 0.f, a1 = 0.f, a2 = 0.f, a3 = 0.f, a4 = 0.f, a5 = 0.f, a6 = 0.f, a7 = 0.f;
            int p = beg;
            for (; p + 8 <= end; p += 8) {
                int4 e0 = *(const int4*)(esrc + p);
                int4 e1 = *(const int4*)(esrc + p + 4);
                uint4 w0 = B16[(size_t)e0.x * 6 + q];
                uint4 w1 = B16[(size_t)e0.y * 6 + q];
                uint4 w2 = B16[(size_t)e0.z * 6 + q];
                uint4 w3 = B16[(size_t)e0.w * 6 + q];
                uint4 w4v = B16[(size_t)e1.x * 6 + q];
                uint4 w5 = B16[(size_t)e1.y * 6 + q];
                uint4 w6 = B16[(size_t)e1.z * 6 + q];
                uint4 w7 = B16[(size_t)e1.w * 6 + q];
                ACC8(w0); ACC8(w1); ACC8(w2); ACC8(w3);
                ACC8(w4v); ACC8(w5); ACC8(w6); ACC8(w7);
            }
            if (p < end) {
                int4 e = *(const int4*)(esrc + p);
                uint4 w0 = B16[(size_t)e.x * 6 + q];
                uint4 w1 = B16[(size_t)e.y * 6 + q];
                uint4 w2 = B16[(size_t)e.z * 6 + q];
                uint4 w3 = B16[(size_t)e.w * 6 + q];
                ACC8(w0); ACC8(w1); ACC8(w2); ACC8(w3);
            }
            float dn = dinv[n];
            float* ap = &ash[ln][q * 8];
            ap[0] = a0 * dn; ap[1] = a1 * dn; ap[2] = a2 * dn; ap[3] = a3 * dn;
            ap[4] = a4 * dn; ap[5] = a5 * dn; ap[6] = a6 * dn; ap[7] = a7 * dn;
        }
    }
    __syncthreads();
    if (t < NPB * 4) {
        int ln = t >> 2, o4 = t & 3;
        int n = nbase + ln;
        if (n < N) {
            float4 sum = make_float4(0.f, 0.f, 0.f, 0.f);
#pragma unroll
            for (int k = 0; k < 3; ++k) {
                ushort4 rq = R16s[(size_t)n * 12 + k * 4 + o4];
                float4 d;
                d.x = bf2f(rq.x); d.y = bf2f(rq.y); d.z = bf2f(rq.z); d.w = bf2f(rq.w);
#pragma unroll
                for (int i = 0; i < 16; ++i) {
                    float a = ash[ln][k * 16 + i];
                    float4 w = Ws[(k * 16 + i) * 4 + o4];
                    d.x = fmaf(a, w.x, d.x);
                    d.y = fmaf(a, w.y, d.y);
                    d.z = fmaf(a, w.z, d.z);
                    d.w = fmaf(a, w.w, d.w);
                }
                d.x = fmaxf(d.x, 0.f); d.y = fmaxf(d.y, 0.f);
                d.z = fmaxf(d.z, 0.f); d.w = fmaxf(d.w, 0.f);
                sum.x += d.x; sum.y += d.y; sum.z += d.z; sum.w += d.w;
            }
            const float third = 1.0f / 3.0f;
            sum.x *= third; sum.y *= third; sum.z *= third; sum.w *= third;
            float4 u0q = ((const float4*)u)[o4];
            float4 u1q = ((const float4*)u)[4 + o4];
            float4 u2q = ((const float4*)u)[8 + o4];
            float d0 = sum.x * u0q.x + sum.y * u0q.y + sum.z * u0q.z + sum.w * u0q.w;
            float d1 = sum.x * u1q.x + sum.y * u1q.y + sum.z * u1q.z + sum.w * u1q.w;
            float d2 = sum.x * u2q.x + sum.y * u2q.y + sum.z * u2q.z + sum.w * u2q.w;
            d0 += __shfl_down(d0, 2, 4); d0 += __shfl_down(d0, 1, 4);
            d1 += __shfl_down(d1, 2, 4); d1 += __shfl_down(d1, 1, 4);
            d2 += __shfl_down(d2, 2, 4); d2 += __shfl_down(d2, 1, 4);
            if (o4 == 0) {
                float dn = dinv[n];
                z0[n] = d0;
                s12[n] = make_float2(d1 * dn, d2 * dn);
            }
        }
    }
}

// ---------------- pass A: scalar prop of (s1,s2): z01 = z0 + dinv*Σs1 ; t2 = dinv²*Σs2 ----------------
__global__ void k_passA(const float2* __restrict__ s12,
                        const int* __restrict__ rowptrp, const int* __restrict__ esrc,
                        const float* __restrict__ dinv, const float* __restrict__ z0,
                        float* __restrict__ z01, float* __restrict__ t2, int N) {
    int n = blockIdx.x * blockDim.x + threadIdx.x;
    if (n >= N) return;
    int rp = rowptrp[n];
    int beg = (rp & 0xFFFFF) << 2;
    int end = beg + ((rp >> 20) << 2);
    float S1 = 0.f, S2 = 0.f;
    int p = beg;
    for (; p + 8 <= end; p += 8) {
        int4 e0 = *(const int4*)(esrc + p);
        int4 e1 = *(const int4*)(esrc + p + 4);
        float2 v0 = s12[e0.x], v1 = s12[e0.y], v2 = s12[e0.z], v3 = s12[e0.w];
        float2 v4 = s12[e1.x], v5 = s12[e1.y], v6 = s12[e1.z], v7 = s12[e1.w];
        S1 += ((v0.x + v1.x) + (v2.x + v3.x)) + ((v4.x + v5.x) + (v6.x + v7.x));
        S2 += ((v0.y + v1.y) + (v2.y + v3.y)) + ((v4.y + v5.y) + (v6.y + v7.y));
    }
    if (p < end) {
        int4 e = *(const int4*)(esrc + p);
        float2 v0 = s12[e.x], v1 = s12[e.y], v2 = s12[e.z], v3 = s12[e.w];
        S1 += (v0.x + v1.x) + (v2.x + v3.x);
        S2 += (v0.y + v1.y) + (v2.y + v3.y);
    }
    float dn = dinv[n];
    z01[n] = z0[n] + dn * S1;
    t2[n] = dn * dn * S2;
}

// ---------------- pass B: scalar prop of t2 + final score + pool ----------------
__global__ void k_passB(const float* __restrict__ t2,
                        const int* __restrict__ rowptrp, const int* __restrict__ esrc,
                        const float* __restrict__ dinv, const float* __restrict__ z01,
                        const float* __restrict__ sv, const float* __restrict__ u,
                        const int* __restrict__ batch, float* __restrict__ out, int N) {
    int n = blockIdx.x * blockDim.x + threadIdx.x;
    if (n >= N) return;
    int rp = rowptrp[n];
    int beg = (rp & 0xFFFFF) << 2;
    int end = beg + ((rp >> 20) << 2);
    float S = 0.f;
    int p = beg;
    for (; p + 8 <= end; p += 8) {
        int4 e0 = *(const int4*)(esrc + p);
        int4 e1 = *(const int4*)(esrc + p + 4);
        S += ((t2[e0.x] + t2[e0.y]) + (t2[e0.z] + t2[e0.w]))
           + ((t2[e1.x] + t2[e1.y]) + (t2[e1.z] + t2[e1.w]));
    }
    if (p < end) {
        int4 e = *(const int4*)(esrc + p);
        S += (t2[e.x] + t2[e.y]) + (t2[e.z] + t2[e.w]);
    }
    float v = z01[n] + dinv[n] * S + sv[n] * u[48] + u[49];
    atomicAdd(&out[batch[n]], v);
}

// ---------------- precombine layer-2+head weights; blocks 1..8 init out ----------------
__global__ void k_comb(const float* __restrict__ w2i, const float* __restrict__ w2w,
                       const float* __restrict__ w2r, const float* __restrict__ b2,
                       const float* __restrict__ wg, const float* __restrict__ bg,
                       float* __restrict__ u, float* __restrict__ out) {
    if (blockIdx.x > 0) {
        int g = (blockIdx.x - 1) * 256 + threadIdx.x;
        if (g < NG) out[g] = bg[0];
        return;
    }
    __shared__ float t[3][64];
    int tid = threadIdx.x;
    if (tid < 64) {
#pragma unroll
        for (int k = 0; k < 3; ++k) {
            float a = 0.f;
            for (int j = 0; j < 64; ++j) a = fmaf(w2w[k * 4096 + tid * 64 + j], wg[j], a);
            t[k][tid] = a;
        }
    }
    __syncthreads();
    if (tid < 64) {
        float wgv = wg[tid];
        float tk0 = t[0][tid], tk1 = t[1][tid], tk2 = t[2][tid];
        const float third = 1.0f / 3.0f;
        for (int j = 0; j < 16; ++j) {
            float wi0 = w2i[j * 64 + tid], wi1 = w2i[1024 + j * 64 + tid], wi2 = w2i[2048 + j * 64 + tid];
            float wr0 = w2r[j * 64 + tid], wr1 = w2r[1024 + j * 64 + tid], wr2 = w2r[2048 + j * 64 + tid];
            float a2 = wi0 * tk0 + wi1 * tk1 + wi2 * tk2;
            float a1 = wr0 * tk0 + wr1 * tk1 + wr2 * tk2;
            float a0 = (wr0 + wr1 + wr2) * wgv;
#pragma unroll
            for (int off = 32; off > 0; off >>= 1) {
                a2 += __shfl_down(a2, off, 64);
                a1 += __shfl_down(a1, off, 64);
                a0 += __shfl_down(a0, off, 64);
            }
            if (tid == 0) {
                u[j] = a0 * third;
                u[16 + j] = a1 * third;
                u[32 + j] = a2 * third;
            }
        }
        float b0 = b2[tid], b1v = b2[64 + tid], b2v = b2[128 + tid];
        float c0 = b0 * tk0 + b1v * tk1 + b2v * tk2;
        float c1 = (b0 + b1v + b2v) * wgv;
#pragma unroll
        for (int off = 32; off > 0; off >>= 1) {
            c0 += __shfl_down(c0, off, 64);
            c1 += __shfl_down(c1, off, 64);
        }
        if (tid == 0) {
            u[48] = c0 * third;
            u[49] = c1 * third;
        }
    }
}

extern "C" void kernel_launch(void* const* d_in, const int* in_sizes, int n_in,
                              void* d_out, int out_size, void* d_ws, size_t ws_size,
                              hipStream_t stream) {
    const float* x   = (const float*)d_in[0];
    const int*   ei  = (const int*)d_in[1];
    const int*   batch = (const int*)d_in[2];
    const float* w1i = (const float*)d_in[3];
    const float* w1w = (const float*)d_in[4];
    const float* w1r = (const float*)d_in[5];
    const float* w1b = (const float*)d_in[6];
    const float* w2i = (const float*)d_in[7];
    const float* w2w = (const float*)d_in[8];
    const float* w2r = (const float*)d_in[9];
    const float* w2b = (const float*)d_in[10];
    const float* wg  = (const float*)d_in[11];
    const float* bg  = (const float*)d_in[12];
    float* out = (float*)d_out;

    // workspace layout (all 16B-aligned)
    uint4*  A16  = (uint4*)d_ws;                          // [(N+1)*6] uint4 = bf16[N+1][48]
    uint4*  B16  = A16 + (size_t)(NN + 1) * 6;            // same
    uint4*  R16  = B16 + (size_t)(NN + 1) * 6;            // [N*6] uint4 = bf16[N][48]
    float2* s12  = (float2*)(R16 + (size_t)NN * 6);       // [N+1] (s1,s2)
    float*  t2   = (float*)(s12 + NN + 1);                // [N+1]
    float*  z0   = t2 + NN + 1;                           // [N]
    float*  z01  = z0 + NN;                               // [N]
    float*  dinv = z01 + NN;                              // [N+1]
    float*  sv   = dinv + NN + 1;                         // [N]
    float*  u    = sv + NN;                               // [64]
    int* rowptrp = (int*)(u + 64);                        // [N] packed
    int* gcur    = rowptrp + NN;                          // [512]
    int* pairs   = gcur + 512;                            // [(NBK+1)*CAPQ]
    int* esrc    = pairs + (size_t)(NBK + 1) * CAPQ;      // [NBK*CAPE]

    const int T = 256;

    // ---- CSR build (histogram-free, bucketed) ----
    k_init<<<3, T, 0, stream>>>(gcur, A16, B16, s12, t2, dinv);
    k_part<<<512, T, 0, stream>>>((const int4*)ei, (const int4*)(ei + NE),
                                  gcur, pairs, NE / 4);
    k_bucket<<<NBK, T, 0, stream>>>(pairs, gcur, esrc, rowptrp, dinv, NN);

    // ---- precombined layer-2+head weights + out init ----
    k_comb<<<9, T, 0, stream>>>(w2i, w2w, w2r, w2b, wg, bg, u, out);

    // ---- layer 1 input transforms (A, R both bf16) ----
    k_mmAR<<<2048, T, 0, stream>>>(x, w1i, w1r, w1b, dinv,
                                   (ushort4*)A16, (ushort4*)R16, NN);

    // t=0: B16 = bf16( dinv * relu(prop(A16) + R) * dinv ); also sv
    k_prop48<<<cdiv((long long)NN * 6, T), T, 0, stream>>>(
        A16, R16, rowptrp, esrc, dinv, sv, B16, NN);

    // t=1 prop + post1 fused: z0 = h1·u0 ; s12 = ((h1 dinv)·u1, (h1 dinv)·u2)
    k_proppost<<<cdiv(NN, NPB), T, 0, stream>>>(
        B16, (const ushort4*)R16, w1w, rowptrp, esrc, dinv, u, z0, s12, NN);

    // ---- layer 2, fully scalarized: two scalar-gather passes ----
    k_passA<<<cdiv(NN, T), T, 0, stream>>>(s12, rowptrp, esrc, dinv, z0, z01, t2, NN);
    k_passB<<<cdiv(NN, T), T, 0, stream>>>(t2, rowptrp, esrc, dinv, z01, sv, u, batch, out, NN);
}